// Round 19
// baseline (273.800 us; speedup 1.0000x reference)
//
#include <hip/hip_runtime.h>
#include <hip/hip_bf16.h>
#include <math.h>

#define CIN 64
#define CE  64
#define HH  256
#define WW  256
#define OHW 128
#define PW  288   // padded plane width (16-px halo each side)
#define PH  288
#define WOFF 32144           // wlds offset (shorts): k7 xt = 49*82 slots * 8 shorts
#define TOFF (WOFF + 6144)   // tap-offset table (ints), after 3 wlds buffers
#define SHMEM 76928          // (TOFF + 176 shorts) * 2 bytes

typedef __attribute__((ext_vector_type(8))) short bf16x8;
typedef __attribute__((ext_vector_type(4))) float f32x4;

static __device__ __forceinline__ unsigned short f2bf(float f) {
    __hip_bfloat16 h = __float2bfloat16(f);
    return *reinterpret_cast<unsigned short*>(&h);
}

#define GLOAD16(gsrc, ldst)                                                        \
    __builtin_amdgcn_global_load_lds(                                              \
        (const __attribute__((address_space(1))) void*)(gsrc),                     \
        (__attribute__((address_space(3))) void*)(ldst), 16, 0, 0)

// ---------------- fused: pool partials + x -> bf16 NHWC8 padded (halo = 0) ----------------
template <bool PRE>
__global__ __launch_bounds__(256)
void poolcvt_kernel(const float* __restrict__ x, unsigned short* __restrict__ xbf,
                    float* __restrict__ partial) {
    int blk = blockIdx.x;  // b*8+cb
    int rc = blockIdx.y;   // 0..7 (32-row chunks)
    int tid = threadIdx.x, lane = tid & 63, wv = tid >> 6;
    int c0 = lane * 4;
    const float* xb = x + (size_t)blk * 8 * (HH * WW);
    unsigned short* pl = xbf + (size_t)blk * (PW * PH) * 8;
    float s[8];
#pragma unroll
    for (int j = 0; j < 8; ++j) s[j] = 0.f;
#pragma unroll 1
    for (int rr = wv; rr < 32; rr += 4) {
        int h = rc * 32 + rr;
        float4 v[8];
#pragma unroll
        for (int j = 0; j < 8; ++j)
            v[j] = *reinterpret_cast<const float4*>(xb + (size_t)j * (HH * WW) + h * WW + c0);
#pragma unroll
        for (int j = 0; j < 8; ++j) s[j] += (v[j].x + v[j].y) + (v[j].z + v[j].w);
        if (PRE) {
            size_t o16 = ((size_t)(16 + h) * PW + 16 + c0);  // padded coords, 8-short units
            unsigned short u[4][8];
#pragma unroll
            for (int j = 0; j < 8; ++j) {
                u[0][j] = f2bf(v[j].x);
                u[1][j] = f2bf(v[j].y);
                u[2][j] = f2bf(v[j].z);
                u[3][j] = f2bf(v[j].w);
            }
#pragma unroll
            for (int cc = 0; cc < 4; ++cc)
                *reinterpret_cast<bf16x8*>(pl + (o16 + cc) * 8) =
                    *reinterpret_cast<const bf16x8*>(u[cc]);
        }
    }
    if (PRE) {
        bf16x8 z = (bf16x8)(short)0;
#pragma unroll 1
        for (int i = tid; i < 32 * 32; i += 256) {
            int rr = i >> 5, cc = i & 31;
            int pr = 16 + rc * 32 + rr;
            int pc = (cc < 16) ? cc : (256 + cc);
            *reinterpret_cast<bf16x8*>(pl + ((size_t)pr * PW + pc) * 8) = z;
        }
        if (rc == 0) {
#pragma unroll 1
            for (int i = tid; i < 16 * PW; i += 256)
                *reinterpret_cast<bf16x8*>(pl + (size_t)i * 8) = z;
        }
        if (rc == 7) {
#pragma unroll 1
            for (int i = tid; i < 16 * PW; i += 256)
                *reinterpret_cast<bf16x8*>(pl + ((size_t)(272 * PW) + i) * 8) = z;
        }
    }
#pragma unroll
    for (int j = 0; j < 8; ++j) {
#pragma unroll
        for (int m = 32; m >= 1; m >>= 1) s[j] += __shfl_xor(s[j], m, 64);
    }
    __shared__ float red[4][8];
    if (lane == 0) {
#pragma unroll
        for (int j = 0; j < 8; ++j) red[wv][j] = s[j];
    }
    __syncthreads();
    if (tid < 8) {
        int j = tid;
        float t = (red[0][j] + red[1][j]) + (red[2][j] + red[3][j]);
        partial[(blk * 8 + rc) * 8 + j] = t;
    }
}

// ---------------- gate ----------------
__global__ __launch_bounds__(64)
void gate_kernel(const float* __restrict__ partial, const float* __restrict__ gw,
                 const float* __restrict__ gb, int* __restrict__ sel_idx,
                 float* __restrict__ sel_w) {
    int b = blockIdx.x;
    int c = threadIdx.x;
    float p = 0.f;
#pragma unroll
    for (int rc = 0; rc < 8; ++rc)
        p += partial[(((b * 8 + (c >> 3)) * 8) + rc) * 8 + (c & 7)];
    p *= (1.0f / (HH * WW));
    float l[4];
#pragma unroll
    for (int e = 0; e < 4; ++e) l[e] = p * gw[e * CIN + c];
#pragma unroll
    for (int m = 32; m >= 1; m >>= 1) {
#pragma unroll
        for (int e = 0; e < 4; ++e) l[e] += __shfl_xor(l[e], m, 64);
    }
    if (c == 0) {
        float g[4], s = 0.f;
#pragma unroll
        for (int e = 0; e < 4; ++e) l[e] += gb[e];
        float mx = fmaxf(fmaxf(l[0], l[1]), fmaxf(l[2], l[3]));
#pragma unroll
        for (int e = 0; e < 4; ++e) { g[e] = expf(l[e] - mx); s += g[e]; }
#pragma unroll
        for (int e = 0; e < 4; ++e) g[e] /= s;
        int i1 = 0;
        for (int e = 1; e < 4; ++e) if (g[e] > g[i1]) i1 = e;  // first index wins ties
        int i2 = -1;
        for (int e = 0; e < 4; ++e) {
            if (e == i1) continue;
            if (i2 < 0 || g[e] > g[i2]) i2 = e;
        }
        float den = g[i1] + g[i2] + 1e-8f;
        sel_idx[b * 2 + 0] = i1;
        sel_idx[b * 2 + 1] = i2;
        sel_w[b * 2 + 0] = g[i1] / den;
        sel_w[b * 2 + 1] = g[i2] / den;
    }
}

// ---------------- LPT order ----------------
__global__ void order_kernel(const int* __restrict__ sel_idx, int* __restrict__ ord) {
    if (threadIdx.x == 0) {
        int pos = 0;
        const int pri[4] = {3, 2, 1, 0};
        for (int pi = 0; pi < 4; ++pi)
            for (int bs = 0; bs < 32; ++bs)
                if (sel_idx[bs] == pri[pi]) ord[pos++] = bs;
    }
}

// ---------------- BN fold: per (e,co) -> (inv, beta incl. bias) ----------------
__global__ __launch_bounds__(256)
void bnprep_kernel(const float* __restrict__ b0, const float* __restrict__ b1,
                   const float* __restrict__ b2, const float* __restrict__ b3,
                   const float* __restrict__ bns, const float* __restrict__ bnb,
                   const float* __restrict__ bnm, const float* __restrict__ bnv,
                   float2* __restrict__ cbn) {
    int i = threadIdx.x;  // e*64+co
    int e = i >> 6, co = i & 63;
    const float* be = (e == 0) ? b0 : (e == 1) ? b1 : (e == 2) ? b2 : b3;
    float inv = bns[i] * rsqrtf(bnv[i] + 1e-5f);
    float beta = bnb[i] - bnm[i] * inv + be[co] * inv;
    cbn[i] = make_float2(inv, beta);
}

// ---------------- weight pre-pack (all experts, one launch) ----------------
__global__ __launch_bounds__(256)
void wprep_all_kernel(const float* __restrict__ w0, const float* __restrict__ w1,
                      const float* __restrict__ w2, const float* __restrict__ w3,
                      unsigned short* __restrict__ wq) {
    int cb = blockIdx.x;
    int y = blockIdx.y;  // 0..43
    const float* w;
    int g0, k, GE;
    size_t base;
    if (y < 3)       { w = w0; g0 = y;      k = 3; GE = 3;  base = 0; }
    else if (y < 10) { w = w1; g0 = y - 3;  k = 5; GE = 7;  base = 49152; }
    else if (y < 23) { w = w2; g0 = y - 10; k = 7; GE = 13; base = 163840; }
    else             { w = w3; g0 = y - 23; k = 9; GE = 21; base = 376832; }
    int k2 = k * k;
    int t = threadIdx.x, tl = t >> 6, co = t & 63;
    int tap = g0 * 4 + tl;
    unsigned short vals[8];
#pragma unroll
    for (int j = 0; j < 8; ++j) {
        float v = 0.f;
        if (tap < k2) v = w[(size_t)(co * CIN + cb * 8 + j) * k2 + tap];
        vals[j] = f2bf(v);
    }
    *reinterpret_cast<bf16x8*>(&wq[base + (size_t)(cb * GE + g0) * 2048 + t * 8]) =
        *reinterpret_cast<const bf16x8*>(vals);
}

// ---------------- conv body: 512 thr (8 waves), 16oh x 32ow x 64co per block ----------
template <int K, int D, int GE, bool EVEN, bool PRE>
__device__ __forceinline__ void conv_body(const float* __restrict__ xb,
                                          const unsigned short* __restrict__ xpb,
                                          const unsigned short* __restrict__ wq,
                                          unsigned short* __restrict__ lds,
                                          f32x4 acc[4][4],
                                          int ih0, int iw0, int lane, int wv, int tid) {
    constexpr int K2 = K * K;
    constexpr int TS_H = 31 + (K - 1) * D;
    constexpr int TS_W = 63 + (K - 1) * D;
    constexpr int S = (TS_W + 1) / 2;     // parity slots per row (full lattice)
    constexpr int HPW = S * 8;            // shorts per half-plane row
    constexpr int PITCH = 2 * HPW;        // shorts per row (full lattice)
    constexpr int NRH = (TS_H + 1) / 2, NRW = (TS_W + 1) / 2;  // even lattice dims
    constexpr int NEL = EVEN ? NRH * NRW : TS_H * 2 * S;       // 16B slots
    constexpr int ITER = (NEL + 511) / 512;
    constexpr int DH = EVEN ? D / 2 : 0;
    constexpr size_t PLANE = (size_t)PW * PH * 8;
    constexpr int RSTEP = EVEN ? NRW * 16 : PITCH * 4;  // j-step (2 in rows) bytes
    int p = lane & 15, hi = lane >> 4;
    int wv2 = wv & 3, wh = wv >> 2;  // wave -> (oh quarter, ow half)

    if constexpr (PRE) {
        // hoisted per-block x staging offsets (shorts within a plane)
        int gofs[ITER];
#pragma unroll
        for (int i = 0; i < ITER; ++i) {
            int idx = tid + i * 512;
            if (idx > NEL - 1) idx = NEL - 1;
            int ih, iw;
            if constexpr (EVEN) {
                int r = idx / NRW, c = idx - r * NRW;
                ih = ih0 + 16 + 2 * r;
                iw = iw0 + 16 + 2 * c;
            } else {
                int r = idx / (2 * S), rem = idx - r * (2 * S);
                int half = rem >= S ? 1 : 0;
                int sl = rem - half * S;
                int c = 2 * sl + half;
                if (c > TS_W - 1) c = TS_W - 1;  // junk pad slot, never read back
                ih = ih0 + 16 + r;
                iw = iw0 + 16 + c;
            }
            gofs[i] = (ih * PW + iw) * 8;
        }
        // tap-offset table: toff(t) for t = g*4+hi (byte offset into xt, tap-only part)
        if (tid < 4 * GE) {
            int tapc = tid < K2 ? tid : K2 - 1;  // dummy taps -> clamp (weights are zero)
            int kh = tapc / K, kw = tapc % K;
            int off;
            if constexpr (EVEN)
                off = (DH * kh * NRW + DH * kw) * 16;
            else
                off = D * kh * PITCH * 2 + (kw & 1) * HPW * 2 +
                      (((D * kw) - (kw & 1)) >> 1) * 16;
            *reinterpret_cast<int*>(&lds[TOFF + tid * 2]) = off;
        }
        __syncthreads();
        const int* tab = reinterpret_cast<const int*>(&lds[TOFF]);
        const char* ldsc = reinterpret_cast<const char*>(lds);
        int baseB = EVEN ? ((wv2 * 4 * NRW + p + 16 * wh) * 16)
                         : (wv2 * 16 * PITCH + (p + 16 * wh) * 16);
        bool lowhalf = tid < 256;  // wave-uniform

#pragma unroll 1
        for (int cb = 0; cb < 8; ++cb) {
            // xt readers of prev cb finished before their MFMAs -> plain barrier
            __builtin_amdgcn_s_barrier();
            const unsigned short* xp = xpb + (size_t)cb * PLANE;
#pragma unroll
            for (int i = 0; i < ITER; ++i) {
                if (tid + i * 512 < NEL)
                    GLOAD16(xp + gofs[i], &lds[(tid + i * 512) * 8]);
            }
            const unsigned short* wcb = wq + (size_t)cb * GE * 2048;
            if (lowhalf) {
                GLOAD16(wcb + tid * 8, &lds[WOFF + tid * 8]);                // W0 -> buf0
                GLOAD16(wcb + 2048 + tid * 8, &lds[WOFF + 2048 + tid * 8]);  // W1 -> buf1
            }
            int toffCur = tab[hi];  // g=0
#pragma unroll
            for (int g = 0; g < GE; ++g) {
                // wait discipline (per-thread outstanding-op counts!):
                //  - lower half: newest 1 op = W[g+1] (or W1 at g=0) may fly; rest drained
                //  - upper half: only x-tile loads ever outstanding -> drain fully at g=0
                if (g == GE - 1) {
                    asm volatile("s_waitcnt vmcnt(0)" ::: "memory");
                } else if (g == 0) {
                    if (lowhalf) asm volatile("s_waitcnt vmcnt(1)" ::: "memory");
                    else         asm volatile("s_waitcnt vmcnt(0)" ::: "memory");
                } else {
                    asm volatile("s_waitcnt vmcnt(1)" ::: "memory");
                }
                __builtin_amdgcn_s_barrier();
                // prefetch W[g+2]; its buffer's readers (phase g-1) all passed this barrier
                if (g + 2 < GE && lowhalf)
                    GLOAD16(wcb + (size_t)(g + 2) * 2048 + tid * 8,
                            &lds[WOFF + ((g + 2) % 3) * 2048 + tid * 8]);
                // prefetch next phase's tap offset (register survives the barrier)
                int toffNext = (g + 1 < GE) ? tab[(g + 1) * 4 + hi] : 0;
                const unsigned short* wl = &lds[WOFF + (g % 3) * 2048 + hi * 512 + p * 8];
                bf16x8 a0 = *reinterpret_cast<const bf16x8*>(wl);
                bf16x8 a1 = *reinterpret_cast<const bf16x8*>(wl + 128);
                bf16x8 a2 = *reinterpret_cast<const bf16x8*>(wl + 256);
                bf16x8 a3 = *reinterpret_cast<const bf16x8*>(wl + 384);
                const char* bp = ldsc + (baseB + toffCur);
#pragma unroll
                for (int j = 0; j < 4; ++j) {
                    const bf16x8 bf = *reinterpret_cast<const bf16x8*>(bp + j * RSTEP);
                    acc[j][0] = __builtin_amdgcn_mfma_f32_16x16x32_bf16(a0, bf, acc[j][0], 0, 0, 0);
                    acc[j][1] = __builtin_amdgcn_mfma_f32_16x16x32_bf16(a1, bf, acc[j][1], 0, 0, 0);
                    acc[j][2] = __builtin_amdgcn_mfma_f32_16x16x32_bf16(a2, bf, acc[j][2], 0, 0, 0);
                    acc[j][3] = __builtin_amdgcn_mfma_f32_16x16x32_bf16(a3, bf, acc[j][3], 0, 0, 0);
                }
                toffCur = toffNext;
            }
        }
    } else {
        // fallback: clamp-gather staging, weights from global
#pragma unroll 1
        for (int cb = 0; cb < 8; ++cb) {
            __syncthreads();
            const float* xc8 = xb + (size_t)cb * 8 * (HH * WW);
#pragma unroll 1
            for (int idx = tid; idx < NEL; idx += 512) {
                int ih, iw;
                if constexpr (EVEN) {
                    int r = idx / NRW, c = idx - r * NRW;
                    ih = ih0 + 2 * r; iw = iw0 + 2 * c;
                } else {
                    int r = idx / (2 * S), rem = idx - r * (2 * S);
                    int half = rem >= S ? 1 : 0;
                    int sl = rem - half * S;
                    int c = min(2 * sl + half, TS_W - 1);
                    ih = ih0 + r; iw = iw0 + c;
                }
                int ihc = min(max(ih, 0), HH - 1), iwc = min(max(iw, 0), WW - 1);
                bool ok = ((unsigned)ih < (unsigned)HH) && ((unsigned)iw < (unsigned)WW);
                unsigned short u[8];
                const float* src = xc8 + ihc * WW + iwc;
#pragma unroll
                for (int j = 0; j < 8; ++j) u[j] = f2bf(ok ? src[(size_t)j * (HH * WW)] : 0.f);
                *reinterpret_cast<bf16x8*>(&lds[idx * 8]) = *reinterpret_cast<const bf16x8*>(u);
            }
            __syncthreads();
            const unsigned short* wcb = wq + (size_t)cb * GE * 2048;
#pragma unroll 2
            for (int g = 0; g < GE; ++g) {
                int tap = g * 4 + hi;
                int tapc = tap < K2 ? tap : K2 - 1;
                int kh = tapc / K, kw = tapc % K;
                const unsigned short* wg = wcb + g * 2048 + hi * 512;
                bf16x8 a0 = *reinterpret_cast<const bf16x8*>(wg + p * 8);
                bf16x8 a1 = *reinterpret_cast<const bf16x8*>(wg + 128 + p * 8);
                bf16x8 a2 = *reinterpret_cast<const bf16x8*>(wg + 256 + p * 8);
                bf16x8 a3 = *reinterpret_cast<const bf16x8*>(wg + 384 + p * 8);
#pragma unroll
                for (int j = 0; j < 4; ++j) {
                    const bf16x8* bfp;
                    if constexpr (EVEN) {
                        int ec = p + 16 * wh + (D / 2) * kw;
                        int erb = wv2 * 4 + (D / 2) * kh + j;
                        bfp = reinterpret_cast<const bf16x8*>(&lds[(erb * NRW + ec) * 8]);
                    } else {
                        int ic = 2 * (p + 16 * wh) + D * kw;
                        int bbase = (ic & 1) * HPW + (ic >> 1) * 8;
                        int irb = D * kh + wv2 * 8 + 2 * j;
                        bfp = reinterpret_cast<const bf16x8*>(&lds[irb * PITCH + bbase]);
                    }
                    const bf16x8 bf = *bfp;
                    acc[j][0] = __builtin_amdgcn_mfma_f32_16x16x32_bf16(a0, bf, acc[j][0], 0, 0, 0);
                    acc[j][1] = __builtin_amdgcn_mfma_f32_16x16x32_bf16(a1, bf, acc[j][1], 0, 0, 0);
                    acc[j][2] = __builtin_amdgcn_mfma_f32_16x16x32_bf16(a2, bf, acc[j][2], 0, 0, 0);
                    acc[j][3] = __builtin_amdgcn_mfma_f32_16x16x32_bf16(a3, bf, acc[j][3], 0, 0, 0);
                }
            }
        }
    }
}

// ---------------- unified MoE conv + BN + GELU(tanh) + gate ----------------
template <bool PRE>
__global__ __launch_bounds__(512, 4)
void conv_moe_kernel(const float* __restrict__ x, const unsigned short* __restrict__ xbf,
                     const unsigned short* __restrict__ wq,
                     const float2* __restrict__ cbn,
                     const int* __restrict__ sel_idx, const float* __restrict__ sel_w,
                     const int* __restrict__ ord, float* __restrict__ out) {
    extern __shared__ __align__(16) unsigned short lds[];  // SHMEM = 76928 B

    int bidx = blockIdx.x;
    int bs = ord[bidx >> 5];  // LPT: heavy experts first
    int tile = bidx & 31;     // 8 oh-tiles x 4 ow-tiles
    int b = bs >> 1, slot = bs & 1;
    int e = sel_idx[bs];
    float gwt = sel_w[bs];
    int oh0 = (tile >> 2) * 16, ow0 = (tile & 3) * 32;
    const float* xb = x + (size_t)b * CIN * HH * WW;
    const unsigned short* xpb = xbf + (size_t)b * 8 * (PW * PH) * 8;
    int tid = threadIdx.x, lane = tid & 63, wv = tid >> 6;
    int p = lane & 15, hi = lane >> 4;
    int wv2 = wv & 3, wh = wv >> 2;

    f32x4 acc[4][4];
#pragma unroll
    for (int j = 0; j < 4; ++j)
#pragma unroll
        for (int ct = 0; ct < 4; ++ct) acc[j][ct] = (f32x4){0.f, 0.f, 0.f, 0.f};

    switch (e) {
        case 0:
            conv_body<3, 1, 3, false, PRE>(xb, xpb, wq, lds, acc, oh0 * 2 - 1, ow0 * 2 - 1, lane, wv, tid);
            break;
        case 1:
            conv_body<5, 2, 7, true, PRE>(xb, xpb, wq + 49152, lds, acc, oh0 * 2 - 4, ow0 * 2 - 4, lane, wv, tid);
            break;
        case 2:
            conv_body<7, 3, 13, false, PRE>(xb, xpb, wq + 163840, lds, acc, oh0 * 2 - 9, ow0 * 2 - 9, lane, wv, tid);
            break;
        default:
            conv_body<9, 4, 21, true, PRE>(xb, xpb, wq + 376832, lds, acc, oh0 * 2 - 16, ow0 * 2 - 16, lane, wv, tid);
            break;
    }

    // epilogue: folded BN -> tanh-approx GELU -> gate
    float* ob = out + (size_t)(b * 128 + slot * 64) * (OHW * OHW);
#pragma unroll
    for (int ct = 0; ct < 4; ++ct) {
#pragma unroll
        for (int reg = 0; reg < 4; ++reg) {
            int co = ct * 16 + hi * 4 + reg;
            float2 cb2 = cbn[e * CE + co];
#pragma unroll
            for (int j = 0; j < 4; ++j) {
                float y = acc[j][ct][reg] * cb2.x + cb2.y;
                float u = y * (1.5957691216f + 0.0714295766f * y * y);
                float gl = y / (1.0f + __expf(-u));
                int oh = oh0 + wv2 * 4 + j, ow = ow0 + wh * 16 + p;
                ob[(size_t)co * (OHW * OHW) + oh * OHW + ow] = gl * gwt;
            }
        }
    }
}

extern "C" void kernel_launch(void* const* d_in, const int* in_sizes, int n_in,
                              void* d_out, int out_size, void* d_ws, size_t ws_size,
                              hipStream_t stream) {
    const float* x   = (const float*)d_in[0];
    const float* w0  = (const float*)d_in[1];
    const float* b0  = (const float*)d_in[2];
    const float* w1  = (const float*)d_in[3];
    const float* b1  = (const float*)d_in[4];
    const float* w2  = (const float*)d_in[5];
    const float* b2  = (const float*)d_in[6];
    const float* w3  = (const float*)d_in[7];
    const float* b3  = (const float*)d_in[8];
    const float* bns = (const float*)d_in[9];
    const float* bnb = (const float*)d_in[10];
    const float* bnm = (const float*)d_in[11];
    const float* bnv = (const float*)d_in[12];
    const float* gw  = (const float*)d_in[13];
    const float* gb  = (const float*)d_in[14];
    float* out = (float*)d_out;

    char* ws = (char*)d_ws;
    float* partial = (float*)ws;                          // 32768 B
    int* sel_idx   = (int*)(ws + 32768);                  // 128 B
    float* sel_w   = (float*)(ws + 32896);                // 128 B
    int* ord       = (int*)(ws + 33024);                  // 128 B
    float2* cbn    = (float2*)(ws + 33280);               // 2048 B
    unsigned short* wq = (unsigned short*)(ws + 40960);   // packed weights (1.51 MB)
    unsigned short* xbf = (unsigned short*)(ws + 2097152);  // padded bf16 NHWC8 x
    const size_t NEED = 2097152ull + (size_t)128 * PW * PH * 16;
    bool pre = ws_size >= NEED;

    // opt in to >64 KB dynamic LDS (host-side, idempotent, graph-capture-safe)
    hipFuncSetAttribute(reinterpret_cast<const void*>(&conv_moe_kernel<true>),
                        hipFuncAttributeMaxDynamicSharedMemorySize, SHMEM);
    hipFuncSetAttribute(reinterpret_cast<const void*>(&conv_moe_kernel<false>),
                        hipFuncAttributeMaxDynamicSharedMemorySize, SHMEM);

    if (pre) poolcvt_kernel<true><<<dim3(128, 8), 256, 0, stream>>>(x, xbf, partial);
    else     poolcvt_kernel<false><<<dim3(128, 8), 256, 0, stream>>>(x, xbf, partial);
    gate_kernel<<<dim3(16), 64, 0, stream>>>(partial, gw, gb, sel_idx, sel_w);
    order_kernel<<<dim3(1), 64, 0, stream>>>(sel_idx, ord);
    bnprep_kernel<<<dim3(1), 256, 0, stream>>>(b0, b1, b2, b3, bns, bnb, bnm, bnv, cbn);
    wprep_all_kernel<<<dim3(8, 44), 256, 0, stream>>>(w0, w1, w2, w3, wq);

    if (pre)
        conv_moe_kernel<true><<<dim3(1024), 512, SHMEM, stream>>>(
            x, xbf, wq, cbn, sel_idx, sel_w, ord, out);
    else
        conv_moe_kernel<false><<<dim3(1024), 512, SHMEM, stream>>>(
            x, xbf, wq, cbn, sel_idx, sel_w, ord, out);
}

// Round 20
// 257.837 us; speedup vs baseline: 1.0619x; 1.0619x over previous
//
#include <hip/hip_runtime.h>
#include <hip/hip_bf16.h>
#include <math.h>

#define CIN 64
#define CE  64
#define HH  256
#define WW  256
#define OHW 128
#define PW  288   // padded plane width (16-px halo each side)
#define PH  288
#define WOFF 19600           // wlds offset (shorts) within the shared block
#define TOFF (WOFF + 6144)   // tap-offset table (ints), after 3 wlds buffers

typedef __attribute__((ext_vector_type(8))) short bf16x8;
typedef __attribute__((ext_vector_type(4))) float f32x4;

static __device__ __forceinline__ unsigned short f2bf(float f) {
    __hip_bfloat16 h = __float2bfloat16(f);
    return *reinterpret_cast<unsigned short*>(&h);
}

#define GLOAD16(gsrc, ldst)                                                        \
    __builtin_amdgcn_global_load_lds(                                              \
        (const __attribute__((address_space(1))) void*)(gsrc),                     \
        (__attribute__((address_space(3))) void*)(ldst), 16, 0, 0)

// ---------------- fused: pool partials + x -> bf16 NHWC8 padded (halo = 0) ----------------
template <bool PRE>
__global__ __launch_bounds__(256)
void poolcvt_kernel(const float* __restrict__ x, unsigned short* __restrict__ xbf,
                    float* __restrict__ partial) {
    int blk = blockIdx.x;  // b*8+cb
    int rc = blockIdx.y;   // 0..7 (32-row chunks)
    int tid = threadIdx.x, lane = tid & 63, wv = tid >> 6;
    int c0 = lane * 4;
    const float* xb = x + (size_t)blk * 8 * (HH * WW);
    unsigned short* pl = xbf + (size_t)blk * (PW * PH) * 8;
    float s[8];
#pragma unroll
    for (int j = 0; j < 8; ++j) s[j] = 0.f;
#pragma unroll 1
    for (int rr = wv; rr < 32; rr += 4) {
        int h = rc * 32 + rr;
        float4 v[8];
#pragma unroll
        for (int j = 0; j < 8; ++j)
            v[j] = *reinterpret_cast<const float4*>(xb + (size_t)j * (HH * WW) + h * WW + c0);
#pragma unroll
        for (int j = 0; j < 8; ++j) s[j] += (v[j].x + v[j].y) + (v[j].z + v[j].w);
        if (PRE) {
            size_t o16 = ((size_t)(16 + h) * PW + 16 + c0);  // padded coords, 8-short units
            unsigned short u[4][8];
#pragma unroll
            for (int j = 0; j < 8; ++j) {
                u[0][j] = f2bf(v[j].x);
                u[1][j] = f2bf(v[j].y);
                u[2][j] = f2bf(v[j].z);
                u[3][j] = f2bf(v[j].w);
            }
#pragma unroll
            for (int cc = 0; cc < 4; ++cc)
                *reinterpret_cast<bf16x8*>(pl + (o16 + cc) * 8) =
                    *reinterpret_cast<const bf16x8*>(u[cc]);
        }
    }
    if (PRE) {
        bf16x8 z = (bf16x8)(short)0;
#pragma unroll 1
        for (int i = tid; i < 32 * 32; i += 256) {
            int rr = i >> 5, cc = i & 31;
            int pr = 16 + rc * 32 + rr;
            int pc = (cc < 16) ? cc : (256 + cc);
            *reinterpret_cast<bf16x8*>(pl + ((size_t)pr * PW + pc) * 8) = z;
        }
        if (rc == 0) {
#pragma unroll 1
            for (int i = tid; i < 16 * PW; i += 256)
                *reinterpret_cast<bf16x8*>(pl + (size_t)i * 8) = z;
        }
        if (rc == 7) {
#pragma unroll 1
            for (int i = tid; i < 16 * PW; i += 256)
                *reinterpret_cast<bf16x8*>(pl + ((size_t)(272 * PW) + i) * 8) = z;
        }
    }
#pragma unroll
    for (int j = 0; j < 8; ++j) {
#pragma unroll
        for (int m = 32; m >= 1; m >>= 1) s[j] += __shfl_xor(s[j], m, 64);
    }
    __shared__ float red[4][8];
    if (lane == 0) {
#pragma unroll
        for (int j = 0; j < 8; ++j) red[wv][j] = s[j];
    }
    __syncthreads();
    if (tid < 8) {
        int j = tid;
        float t = (red[0][j] + red[1][j]) + (red[2][j] + red[3][j]);
        partial[(blk * 8 + rc) * 8 + j] = t;
    }
}

// ---------------- gate ----------------
__global__ __launch_bounds__(64)
void gate_kernel(const float* __restrict__ partial, const float* __restrict__ gw,
                 const float* __restrict__ gb, int* __restrict__ sel_idx,
                 float* __restrict__ sel_w) {
    int b = blockIdx.x;
    int c = threadIdx.x;
    float p = 0.f;
#pragma unroll
    for (int rc = 0; rc < 8; ++rc)
        p += partial[(((b * 8 + (c >> 3)) * 8) + rc) * 8 + (c & 7)];
    p *= (1.0f / (HH * WW));
    float l[4];
#pragma unroll
    for (int e = 0; e < 4; ++e) l[e] = p * gw[e * CIN + c];
#pragma unroll
    for (int m = 32; m >= 1; m >>= 1) {
#pragma unroll
        for (int e = 0; e < 4; ++e) l[e] += __shfl_xor(l[e], m, 64);
    }
    if (c == 0) {
        float g[4], s = 0.f;
#pragma unroll
        for (int e = 0; e < 4; ++e) l[e] += gb[e];
        float mx = fmaxf(fmaxf(l[0], l[1]), fmaxf(l[2], l[3]));
#pragma unroll
        for (int e = 0; e < 4; ++e) { g[e] = expf(l[e] - mx); s += g[e]; }
#pragma unroll
        for (int e = 0; e < 4; ++e) g[e] /= s;
        int i1 = 0;
        for (int e = 1; e < 4; ++e) if (g[e] > g[i1]) i1 = e;  // first index wins ties
        int i2 = -1;
        for (int e = 0; e < 4; ++e) {
            if (e == i1) continue;
            if (i2 < 0 || g[e] > g[i2]) i2 = e;
        }
        float den = g[i1] + g[i2] + 1e-8f;
        sel_idx[b * 2 + 0] = i1;
        sel_idx[b * 2 + 1] = i2;
        sel_w[b * 2 + 0] = g[i1] / den;
        sel_w[b * 2 + 1] = g[i2] / den;
    }
}

// ---------------- fused prep: LPT order (thread 0) + BN fold (all threads) ----------------
__global__ __launch_bounds__(256)
void prep_kernel(const int* __restrict__ sel_idx, int* __restrict__ ord,
                 const float* __restrict__ b0, const float* __restrict__ b1,
                 const float* __restrict__ b2, const float* __restrict__ b3,
                 const float* __restrict__ bns, const float* __restrict__ bnb,
                 const float* __restrict__ bnm, const float* __restrict__ bnv,
                 float2* __restrict__ cbn) {
    int i = threadIdx.x;  // e*64+co
    int e = i >> 6, co = i & 63;
    const float* be = (e == 0) ? b0 : (e == 1) ? b1 : (e == 2) ? b2 : b3;
    float inv = bns[i] * rsqrtf(bnv[i] + 1e-5f);
    float beta = bnb[i] - bnm[i] * inv + be[co] * inv;
    cbn[i] = make_float2(inv, beta);
    if (i == 0) {
        int pos = 0;
        const int pri[4] = {3, 2, 1, 0};  // GE: 21, 13, 7, 3 — heavy first
        for (int pi = 0; pi < 4; ++pi)
            for (int bs = 0; bs < 32; ++bs)
                if (sel_idx[bs] == pri[pi]) ord[pos++] = bs;
    }
}

// ---------------- weight pre-pack (all experts, one launch) ----------------
__global__ __launch_bounds__(256)
void wprep_all_kernel(const float* __restrict__ w0, const float* __restrict__ w1,
                      const float* __restrict__ w2, const float* __restrict__ w3,
                      unsigned short* __restrict__ wq) {
    int cb = blockIdx.x;
    int y = blockIdx.y;  // 0..43
    const float* w;
    int g0, k, GE;
    size_t base;
    if (y < 3)       { w = w0; g0 = y;      k = 3; GE = 3;  base = 0; }
    else if (y < 10) { w = w1; g0 = y - 3;  k = 5; GE = 7;  base = 49152; }
    else if (y < 23) { w = w2; g0 = y - 10; k = 7; GE = 13; base = 163840; }
    else             { w = w3; g0 = y - 23; k = 9; GE = 21; base = 376832; }
    int k2 = k * k;
    int t = threadIdx.x, tl = t >> 6, co = t & 63;
    int tap = g0 * 4 + tl;
    unsigned short vals[8];
#pragma unroll
    for (int j = 0; j < 8; ++j) {
        float v = 0.f;
        if (tap < k2) v = w[(size_t)(co * CIN + cb * 8 + j) * k2 + tap];
        vals[j] = f2bf(v);
    }
    *reinterpret_cast<bf16x8*>(&wq[base + (size_t)(cb * GE + g0) * 2048 + t * 8]) =
        *reinterpret_cast<const bf16x8*>(vals);
}

// ---------------- conv body: unrolled phases + LDS tap-offset table (r11/r17) ----------
template <int K, int D, int GE, bool EVEN, bool PRE>
__device__ __forceinline__ void conv_body(const float* __restrict__ xb,
                                          const unsigned short* __restrict__ xpb,
                                          const unsigned short* __restrict__ wq,
                                          unsigned short* __restrict__ lds,
                                          f32x4 acc[4][4],
                                          int ih0, int iw0, int lane, int wv, int tid) {
    constexpr int K2 = K * K;
    constexpr int TS = 31 + (K - 1) * D;
    constexpr int S = (TS + 1) / 2;
    constexpr int HPW = S * 8;
    constexpr int PITCH = 2 * HPW;
    constexpr int NRC = (TS + 1) / 2;
    constexpr int NEL = EVEN ? NRC * NRC : TS * 2 * S;
    constexpr int ITER = (NEL + 255) / 256;
    constexpr int DH = EVEN ? D / 2 : 0;
    constexpr size_t PLANE = (size_t)PW * PH * 8;
    constexpr int RSTEP = EVEN ? NRC * 16 : PITCH * 4;  // j-step in bytes
    int p = lane & 15, hi = lane >> 4;

    if constexpr (PRE) {
        // hoisted per-block x staging offsets (shorts within a plane)
        int gofs[ITER];
#pragma unroll
        for (int i = 0; i < ITER; ++i) {
            int idx = tid + i * 256;
            if (idx > NEL - 1) idx = NEL - 1;
            int ih, iw;
            if constexpr (EVEN) {
                int r = idx / NRC, c = idx - r * NRC;
                ih = ih0 + 16 + 2 * r;
                iw = iw0 + 16 + 2 * c;
            } else {
                int r = idx / (2 * S), rem = idx - r * (2 * S);
                int half = rem >= S ? 1 : 0;
                int sl = rem - half * S;
                int c = 2 * sl + half;
                if (c > TS - 1) c = TS - 1;  // junk pad slot, never read back
                ih = ih0 + 16 + r;
                iw = iw0 + 16 + c;
            }
            gofs[i] = (ih * PW + iw) * 8;
        }
        // tap-offset table: toff(t) for t = g*4+hi (byte offset into xt, tap-only part)
        if (tid < 4 * GE) {
            int tapc = tid < K2 ? tid : K2 - 1;  // dummy taps -> clamp (weights are zero)
            int kh = tapc / K, kw = tapc % K;
            int off;
            if constexpr (EVEN)
                off = (DH * kh * NRC + DH * kw) * 16;
            else
                off = D * kh * PITCH * 2 + (kw & 1) * HPW * 2 +
                      (((D * kw) - (kw & 1)) >> 1) * 16;
            *reinterpret_cast<int*>(&lds[TOFF + tid * 2]) = off;
        }
        __syncthreads();
        const int* tab = reinterpret_cast<const int*>(&lds[TOFF]);
        const char* ldsc = reinterpret_cast<const char*>(lds);
        int baseB = EVEN ? ((wv * 4 * NRC + p) * 16) : (wv * 16 * PITCH + p * 16);

#pragma unroll 1
        for (int cb = 0; cb < 8; ++cb) {
            // xt readers of prev cb finished before their MFMAs -> plain barrier
            __builtin_amdgcn_s_barrier();
            const unsigned short* xp = xpb + (size_t)cb * PLANE;
#pragma unroll
            for (int i = 0; i < ITER; ++i) {
                if (tid + i * 256 < NEL)
                    GLOAD16(xp + gofs[i], &lds[(tid + i * 256) * 8]);
            }
            const unsigned short* wcb = wq + (size_t)cb * GE * 2048;
            GLOAD16(wcb + tid * 8, &lds[WOFF + tid * 8]);                  // W0 -> buf0
            GLOAD16(wcb + 2048 + tid * 8, &lds[WOFF + 2048 + tid * 8]);    // W1 -> buf1
            int toffCur = tab[hi];  // g=0
#pragma unroll
            for (int g = 0; g < GE; ++g) {
                // need x (g=0) and W[g] landed; the single newest W may stay in flight
                if (g == GE - 1) asm volatile("s_waitcnt vmcnt(0)" ::: "memory");
                else             asm volatile("s_waitcnt vmcnt(1)" ::: "memory");
                __builtin_amdgcn_s_barrier();
                // prefetch W[g+2]; its buffer's readers (phase g-1) all passed this barrier
                if (g + 2 < GE)
                    GLOAD16(wcb + (size_t)(g + 2) * 2048 + tid * 8,
                            &lds[WOFF + ((g + 2) % 3) * 2048 + tid * 8]);
                // prefetch next phase's tap offset (register survives the barrier)
                int toffNext = (g + 1 < GE) ? tab[(g + 1) * 4 + hi] : 0;
                const unsigned short* wl = &lds[WOFF + (g % 3) * 2048 + hi * 512 + p * 8];
                bf16x8 a0 = *reinterpret_cast<const bf16x8*>(wl);
                bf16x8 a1 = *reinterpret_cast<const bf16x8*>(wl + 128);
                bf16x8 a2 = *reinterpret_cast<const bf16x8*>(wl + 256);
                bf16x8 a3 = *reinterpret_cast<const bf16x8*>(wl + 384);
                const char* bp = ldsc + (baseB + toffCur);
#pragma unroll
                for (int j = 0; j < 4; ++j) {
                    const bf16x8 bf = *reinterpret_cast<const bf16x8*>(bp + j * RSTEP);
                    acc[j][0] = __builtin_amdgcn_mfma_f32_16x16x32_bf16(a0, bf, acc[j][0], 0, 0, 0);
                    acc[j][1] = __builtin_amdgcn_mfma_f32_16x16x32_bf16(a1, bf, acc[j][1], 0, 0, 0);
                    acc[j][2] = __builtin_amdgcn_mfma_f32_16x16x32_bf16(a2, bf, acc[j][2], 0, 0, 0);
                    acc[j][3] = __builtin_amdgcn_mfma_f32_16x16x32_bf16(a3, bf, acc[j][3], 0, 0, 0);
                }
                toffCur = toffNext;
            }
        }
    } else {
        // fallback: clamp-gather staging, weights from global
#pragma unroll 1
        for (int cb = 0; cb < 8; ++cb) {
            __syncthreads();
            const float* xc8 = xb + (size_t)cb * 8 * (HH * WW);
#pragma unroll 1
            for (int idx = tid; idx < NEL; idx += 256) {
                int ih, iw;
                if constexpr (EVEN) {
                    int r = idx / NRC, c = idx - r * NRC;
                    ih = ih0 + 2 * r; iw = iw0 + 2 * c;
                } else {
                    int r = idx / (2 * S), rem = idx - r * (2 * S);
                    int half = rem >= S ? 1 : 0;
                    int sl = rem - half * S;
                    int c = min(2 * sl + half, TS - 1);
                    ih = ih0 + r; iw = iw0 + c;
                }
                int ihc = min(max(ih, 0), HH - 1), iwc = min(max(iw, 0), WW - 1);
                bool ok = ((unsigned)ih < (unsigned)HH) && ((unsigned)iw < (unsigned)WW);
                unsigned short u[8];
                const float* src = xc8 + ihc * WW + iwc;
#pragma unroll
                for (int j = 0; j < 8; ++j) u[j] = f2bf(ok ? src[(size_t)j * (HH * WW)] : 0.f);
                *reinterpret_cast<bf16x8*>(&lds[idx * 8]) = *reinterpret_cast<const bf16x8*>(u);
            }
            __syncthreads();
            const unsigned short* wcb = wq + (size_t)cb * GE * 2048;
#pragma unroll 2
            for (int g = 0; g < GE; ++g) {
                int tap = g * 4 + hi;
                int tapc = tap < K2 ? tap : K2 - 1;
                int kh = tapc / K, kw = tapc % K;
                const unsigned short* wg = wcb + g * 2048 + hi * 512;
                bf16x8 a0 = *reinterpret_cast<const bf16x8*>(wg + p * 8);
                bf16x8 a1 = *reinterpret_cast<const bf16x8*>(wg + 128 + p * 8);
                bf16x8 a2 = *reinterpret_cast<const bf16x8*>(wg + 256 + p * 8);
                bf16x8 a3 = *reinterpret_cast<const bf16x8*>(wg + 384 + p * 8);
                if constexpr (EVEN) {
                    int ec = p + (D / 2) * kw;
                    int erb = wv * 4 + (D / 2) * kh;
#pragma unroll
                    for (int j = 0; j < 4; ++j) {
                        const bf16x8 bf = *reinterpret_cast<const bf16x8*>(
                            &lds[((erb + j) * NRC + ec) * 8]);
                        acc[j][0] = __builtin_amdgcn_mfma_f32_16x16x32_bf16(a0, bf, acc[j][0], 0, 0, 0);
                        acc[j][1] = __builtin_amdgcn_mfma_f32_16x16x32_bf16(a1, bf, acc[j][1], 0, 0, 0);
                        acc[j][2] = __builtin_amdgcn_mfma_f32_16x16x32_bf16(a2, bf, acc[j][2], 0, 0, 0);
                        acc[j][3] = __builtin_amdgcn_mfma_f32_16x16x32_bf16(a3, bf, acc[j][3], 0, 0, 0);
                    }
                } else {
                    int ic = 2 * p + D * kw;
                    int bbase = (ic & 1) * HPW + (ic >> 1) * 8;
                    int irb = D * kh + wv * 8;
#pragma unroll
                    for (int j = 0; j < 4; ++j) {
                        const bf16x8 bf = *reinterpret_cast<const bf16x8*>(
                            &lds[(irb + 2 * j) * PITCH + bbase]);
                        acc[j][0] = __builtin_amdgcn_mfma_f32_16x16x32_bf16(a0, bf, acc[j][0], 0, 0, 0);
                        acc[j][1] = __builtin_amdgcn_mfma_f32_16x16x32_bf16(a1, bf, acc[j][1], 0, 0, 0);
                        acc[j][2] = __builtin_amdgcn_mfma_f32_16x16x32_bf16(a2, bf, acc[j][2], 0, 0, 0);
                        acc[j][3] = __builtin_amdgcn_mfma_f32_16x16x32_bf16(a3, bf, acc[j][3], 0, 0, 0);
                    }
                }
            }
        }
    }
}

// ---------------- unified MoE conv + BN + GELU(tanh) + gate ----------------
template <bool PRE>
__global__ __launch_bounds__(256, 3)
void conv_moe_kernel(const float* __restrict__ x, const unsigned short* __restrict__ xbf,
                     const unsigned short* __restrict__ wq,
                     const float2* __restrict__ cbn,
                     const int* __restrict__ sel_idx, const float* __restrict__ sel_w,
                     const int* __restrict__ ord, float* __restrict__ out) {
    // xt (19600) + 3 wlds bufs (6144) + toff table (176) shorts = 51840 B
    __shared__ __align__(16) unsigned short lds[TOFF + 176];

    int bidx = blockIdx.x;
    int bs = ord[bidx >> 6];  // LPT: heavy experts first
    int tile = bidx & 63;
    int b = bs >> 1, slot = bs & 1;
    int e = sel_idx[bs];
    float gwt = sel_w[bs];
    int oh0 = (tile >> 3) * 16, ow0 = (tile & 7) * 16;
    const float* xb = x + (size_t)b * CIN * HH * WW;
    const unsigned short* xpb = xbf + (size_t)b * 8 * (PW * PH) * 8;
    int tid = threadIdx.x, lane = tid & 63, wv = tid >> 6;
    int p = lane & 15, hi = lane >> 4;

    f32x4 acc[4][4];
#pragma unroll
    for (int j = 0; j < 4; ++j)
#pragma unroll
        for (int ct = 0; ct < 4; ++ct) acc[j][ct] = (f32x4){0.f, 0.f, 0.f, 0.f};

    switch (e) {
        case 0:
            conv_body<3, 1, 3, false, PRE>(xb, xpb, wq, lds, acc, oh0 * 2 - 1, ow0 * 2 - 1, lane, wv, tid);
            break;
        case 1:
            conv_body<5, 2, 7, true, PRE>(xb, xpb, wq + 49152, lds, acc, oh0 * 2 - 4, ow0 * 2 - 4, lane, wv, tid);
            break;
        case 2:
            conv_body<7, 3, 13, false, PRE>(xb, xpb, wq + 163840, lds, acc, oh0 * 2 - 9, ow0 * 2 - 9, lane, wv, tid);
            break;
        default:
            conv_body<9, 4, 21, true, PRE>(xb, xpb, wq + 376832, lds, acc, oh0 * 2 - 16, ow0 * 2 - 16, lane, wv, tid);
            break;
    }

    // epilogue: folded BN -> tanh-approx GELU (|err| <= ~3e-3, threshold 6.6e-2) -> gate
    float* ob = out + (size_t)(b * 128 + slot * 64) * (OHW * OHW);
#pragma unroll
    for (int ct = 0; ct < 4; ++ct) {
#pragma unroll
        for (int reg = 0; reg < 4; ++reg) {
            int co = ct * 16 + hi * 4 + reg;
            float2 cb2 = cbn[e * CE + co];
#pragma unroll
            for (int j = 0; j < 4; ++j) {
                float y = acc[j][ct][reg] * cb2.x + cb2.y;
                float u = y * (1.5957691216f + 0.0714295766f * y * y);
                float gl = y / (1.0f + __expf(-u));
                int oh = oh0 + wv * 4 + j, ow = ow0 + p;
                ob[(size_t)co * (OHW * OHW) + oh * OHW + ow] = gl * gwt;
            }
        }
    }
}

extern "C" void kernel_launch(void* const* d_in, const int* in_sizes, int n_in,
                              void* d_out, int out_size, void* d_ws, size_t ws_size,
                              hipStream_t stream) {
    const float* x   = (const float*)d_in[0];
    const float* w0  = (const float*)d_in[1];
    const float* b0  = (const float*)d_in[2];
    const float* w1  = (const float*)d_in[3];
    const float* b1  = (const float*)d_in[4];
    const float* w2  = (const float*)d_in[5];
    const float* b2  = (const float*)d_in[6];
    const float* w3  = (const float*)d_in[7];
    const float* b3  = (const float*)d_in[8];
    const float* bns = (const float*)d_in[9];
    const float* bnb = (const float*)d_in[10];
    const float* bnm = (const float*)d_in[11];
    const float* bnv = (const float*)d_in[12];
    const float* gw  = (const float*)d_in[13];
    const float* gb  = (const float*)d_in[14];
    float* out = (float*)d_out;

    char* ws = (char*)d_ws;
    float* partial = (float*)ws;                          // 32768 B
    int* sel_idx   = (int*)(ws + 32768);                  // 128 B
    float* sel_w   = (float*)(ws + 32896);                // 128 B
    int* ord       = (int*)(ws + 33024);                  // 128 B
    float2* cbn    = (float2*)(ws + 33280);               // 2048 B
    unsigned short* wq = (unsigned short*)(ws + 40960);   // packed weights (1.51 MB)
    unsigned short* xbf = (unsigned short*)(ws + 2097152);  // padded bf16 NHWC8 x
    const size_t NEED = 2097152ull + (size_t)128 * PW * PH * 16;
    bool pre = ws_size >= NEED;

    if (pre) poolcvt_kernel<true><<<dim3(128, 8), 256, 0, stream>>>(x, xbf, partial);
    else     poolcvt_kernel<false><<<dim3(128, 8), 256, 0, stream>>>(x, xbf, partial);
    gate_kernel<<<dim3(16), 64, 0, stream>>>(partial, gw, gb, sel_idx, sel_w);
    prep_kernel<<<dim3(1), 256, 0, stream>>>(sel_idx, ord, b0, b1, b2, b3,
                                             bns, bnb, bnm, bnv, cbn);
    wprep_all_kernel<<<dim3(8, 44), 256, 0, stream>>>(w0, w1, w2, w3, wq);

    if (pre)
        conv_moe_kernel<true><<<dim3(2048), 256, 0, stream>>>(
            x, xbf, wq, cbn, sel_idx, sel_w, ord, out);
    else
        conv_moe_kernel<false><<<dim3(2048), 256, 0, stream>>>(
            x, xbf, wq, cbn, sel_idx, sel_w, ord, out);
}